// Round 6
// baseline (1127.036 us; speedup 1.0000x reference)
//
#include <hip/hip_runtime.h>
#include <hip/hip_bf16.h>

// ---------------------------------------------------------------------------
// GAT 2-layer, N=16384 nodes, D=512, H=8, E=524288 edges (+self loops)
// GEMMs: split-bf16 3-term MFMA (32x32x16), slot-major LDS, global_load_lds,
// K-split x2 + deterministic combine. Node kernels: CSR softmax + float4
// gather, XCD-pinned per graph. alpha1 fused into node0.
// ---------------------------------------------------------------------------

#define NNODES 16384

typedef unsigned short u16;
typedef unsigned int u32;
typedef __attribute__((ext_vector_type(8))) __bf16 bf16x8;
typedef __attribute__((ext_vector_type(4))) float f32x4;
typedef __attribute__((ext_vector_type(16))) float f32x16;

__device__ __forceinline__ u16 f2bf(float v) {
    u32 u = __builtin_bit_cast(u32, v);
    u32 r = (u + 0x7fffu + ((u >> 16) & 1u)) >> 16;
    return (u16)r;
}
__device__ __forceinline__ float bf2f(u16 s) {
    u32 u = ((u32)s) << 16;
    return __builtin_bit_cast(float, u);
}
__device__ __forceinline__ void split2(float v, u16& h, u16& l) {
    h = f2bf(v);
    l = f2bf(v - bf2f(h));
}

// async global->LDS, 16B per lane; LDS dest is wave-uniform base + lane*16
__device__ __forceinline__ void gload_lds16(const u16* g, u16* l) {
    __builtin_amdgcn_global_load_lds(
        (__attribute__((address_space(1))) void*)(void*)(g),
        (__attribute__((address_space(3))) void*)(void*)(l), 16, 0, 0);
}

// ------------------------------ CSR build ---------------------------------
__global__ void zero_k(int* p, int n) {
    int i = blockIdx.x * 256 + threadIdx.x;
    if (i < n) p[i] = 0;
}

__global__ void count_k(const int* __restrict__ dst, int E, int* __restrict__ deg) {
    int i = blockIdx.x * 256 + threadIdx.x;
    if (i < E) atomicAdd(&deg[dst[i]], 1);
}

__global__ __launch_bounds__(1024) void scan_k(const int* __restrict__ deg,
                                               int* __restrict__ indptr,
                                               int* __restrict__ cursor, int n) {
    __shared__ int sums[1024];
    int t = threadIdx.x;
    int base = t * 16;
    int local[16];
    int s = 0;
    #pragma unroll
    for (int i = 0; i < 16; i++) { local[i] = s; s += deg[base + i]; }
    sums[t] = s;
    __syncthreads();
    for (int off = 1; off < 1024; off <<= 1) {
        int v = (t >= off) ? sums[t - off] : 0;
        __syncthreads();
        sums[t] += v;
        __syncthreads();
    }
    int base_sum = (t == 0) ? 0 : sums[t - 1];
    #pragma unroll
    for (int i = 0; i < 16; i++) {
        int v = base_sum + local[i];
        indptr[base + i] = v;
        cursor[base + i] = v;
    }
    if (t == 1023) indptr[n] = base_sum + s;
}

__global__ void scatter_k(const int* __restrict__ src, const int* __restrict__ dst,
                          int E, int* __restrict__ cursor, int* __restrict__ csr) {
    int i = blockIdx.x * 256 + threadIdx.x;
    if (i < E) {
        int pos = atomicAdd(&cursor[dst[i]], 1);
        csr[pos] = src[i];
    }
}

// ------------------------- split-bf16 prep kernels -------------------------
__global__ void prepx_k(const float* __restrict__ x, u16* __restrict__ xh,
                        u16* __restrict__ xl) {
    int idx = blockIdx.x * 256 + threadIdx.x;
    int e = idx << 2;
    int n = e >> 9, k = e & 511;
    int g = n >> 10, s = n & 1023;
    float4 v = *(const float4*)(x + ((size_t)(s * 16 + g) << 9) + k);
    u16 h[4], l[4];
    split2(v.x, h[0], l[0]);
    split2(v.y, h[1], l[1]);
    split2(v.z, h[2], l[2]);
    split2(v.w, h[3], l[3]);
    size_t o = ((size_t)n << 9) + k;
    *(ushort4*)(xh + o) = make_ushort4(h[0], h[1], h[2], h[3]);
    *(ushort4*)(xl + o) = make_ushort4(l[0], l[1], l[2], l[3]);
}

__global__ __launch_bounds__(256) void prepW0_k(const float* __restrict__ W0,
                                                u16* __restrict__ Wh,
                                                u16* __restrict__ Wl) {
    int n = blockIdx.x;
    for (int k = threadIdx.x; k < 512; k += 256) {
        float v = W0[(size_t)k * 512 + n];
        u16 h, l;
        split2(v, h, l);
        Wh[(size_t)n * 512 + k] = h;
        Wl[(size_t)n * 512 + k] = l;
    }
}

__global__ __launch_bounds__(256) void prepW1_k(const float* __restrict__ W1,
                                                u16* __restrict__ Bh,
                                                u16* __restrict__ Bl) {
    int c = blockIdx.x;
    for (int j = threadIdx.x; j < 4096; j += 256) {
        int hh = j >> 9, k = j & 511;
        float v = W1[(size_t)k * 4096 + hh * 512 + c] * 0.125f;
        u16 h, l;
        split2(v, h, l);
        Bh[(size_t)c * 4096 + j] = h;
        Bl[(size_t)c * 4096 + j] = l;
    }
}

// ---------------------------------------------------------------------------
// Split-bf16 MFMA GEMM: C[M,512] = A[M,K] @ Bt[512,K]^T  (3 MFMA per frag pair)
// BM=128, BN=128, BK=32, 4 waves (2x2, 64x64 each) using mfma_f32_32x32x16.
// LDS layout slot-major: 16B chunk (row, slot) lives at chunkidx slot*128+row
// -> fragment reads are 32 consecutive 16B addresses (conflict-free), while
// global_load_lds dest stays linear (permutation applied on the source addr).
// NS=1: direct store (+bias/ELU if MODE==1).  NS=2: K split across
// blockIdx.z into partials P0/P1 (deterministic combine pass follows).
// ---------------------------------------------------------------------------
template <int MODE, int NS>
__global__ __launch_bounds__(256) void mgemm2_k(
    const u16* __restrict__ Ah, const u16* __restrict__ Al,
    const u16* __restrict__ Bh, const u16* __restrict__ Bl,
    float* __restrict__ C, int K, const float* __restrict__ bias,
    float* __restrict__ P0, float* __restrict__ P1) {
    __shared__ u16 smem[16384];  // 32 KB: 4 planes x 8 KB
    u16* sAh = smem;
    u16* sAl = smem + 4096;
    u16* sBh = smem + 8192;
    u16* sBl = smem + 12288;

    // XCD-aware bijective tile remap (assumes round-robin dispatch id%8)
    int bx, by, bz;
    {
        int orig = blockIdx.x + (blockIdx.y << 2) +
                   blockIdx.z * (gridDim.y << 2);
        int k8 = orig & 7, i8 = orig >> 3;
        if (NS == 2) {
            // xcd = (col-tile, k-half): B slice (2 MB) stays L2-resident
            bx = k8 & 3; bz = k8 >> 2; by = i8;
        } else {
            // chunked: each XCD gets contiguous rows, all col-tiles (A reuse)
            int nl = k8 * (gridDim.y >> 1) + i8;  // nwg/8 = 4*gridY/8
            bx = nl & 3; by = nl >> 2; bz = 0;
        }
    }

    int t = threadIdx.x;
    int lane = t & 63, w = t >> 6;
    int wr = w >> 1, wc = w & 1;
    int row0 = by * 128, col0 = bx * 128;
    int kbeg = (NS == 2) ? bz * (K >> 1) : 0;
    int kcnt = (NS == 2) ? (K >> 1) : K;

    f32x16 acc[2][2];
    #pragma unroll
    for (int i = 0; i < 2; i++)
        #pragma unroll
        for (int j = 0; j < 2; j++)
            #pragma unroll
            for (int q = 0; q < 16; q++) acc[i][j][q] = 0.f;

    // staging role: one plane per wave, 8 segments of 1 KB each
    const u16* gb;
    u16* lb;
    int g0;
    if (w == 0) { gb = Ah; lb = sAh; g0 = row0; }
    else if (w == 1) { gb = Al; lb = sAl; g0 = row0; }
    else if (w == 2) { gb = Bh; lb = sBh; g0 = col0; }
    else { gb = Bl; lb = sBl; g0 = col0; }

    int r32 = lane & 31, kb5 = lane >> 5;

    for (int kk = 0; kk < kcnt; kk += 32) {
        int k0 = kbeg + kk;
        // seg s: rows (s&1)*64+lane, k-slot s>>1  ->  LDS chunks s*64..s*64+63
        #pragma unroll
        for (int s = 0; s < 8; s++) {
            const u16* g = gb + (size_t)(g0 + (s & 1) * 64 + lane) * K + k0 +
                           ((s >> 1) << 3);
            gload_lds16(g, lb + s * 512);
        }
        __syncthreads();

        #pragma unroll
        for (int ks = 0; ks < 2; ks++) {
            int slot = ks * 2 + kb5;
            bf16x8 a_h[2], a_l[2], b_h[2], b_l[2];
            #pragma unroll
            for (int i = 0; i < 2; i++) {
                int off = (slot * 128 + wr * 64 + i * 32 + r32) * 8;
                a_h[i] = *(const bf16x8*)(sAh + off);
                a_l[i] = *(const bf16x8*)(sAl + off);
            }
            #pragma unroll
            for (int j = 0; j < 2; j++) {
                int off = (slot * 128 + wc * 64 + j * 32 + r32) * 8;
                b_h[j] = *(const bf16x8*)(sBh + off);
                b_l[j] = *(const bf16x8*)(sBl + off);
            }
            #pragma unroll
            for (int i = 0; i < 2; i++)
                #pragma unroll
                for (int j = 0; j < 2; j++) {
                    acc[i][j] = __builtin_amdgcn_mfma_f32_32x32x16_bf16(
                        a_l[i], b_h[j], acc[i][j], 0, 0, 0);
                    acc[i][j] = __builtin_amdgcn_mfma_f32_32x32x16_bf16(
                        a_h[i], b_l[j], acc[i][j], 0, 0, 0);
                    acc[i][j] = __builtin_amdgcn_mfma_f32_32x32x16_bf16(
                        a_h[i], b_h[j], acc[i][j], 0, 0, 0);
                }
        }
        __syncthreads();
    }

    float* dst = (NS == 2) ? (bz == 0 ? P0 : P1) : C;
    #pragma unroll
    for (int i = 0; i < 2; i++) {
        #pragma unroll
        for (int j = 0; j < 2; j++) {
            int col = col0 + wc * 64 + j * 32 + r32;
            float bv = (MODE == 1 && NS == 1) ? bias[col] : 0.f;
            f32x16 v = acc[i][j];
            #pragma unroll
            for (int q = 0; q < 16; q++) {
                int row = row0 + wr * 64 + i * 32 + (q & 3) + ((q >> 2) << 3) +
                          (kb5 << 2);
                float o = v[q] + bv;
                if (MODE == 1 && NS == 1) o = o > 0.f ? o : __expf(o) - 1.f;
                dst[(size_t)row * 512 + col] = o;
            }
        }
    }
}

// combine K-split partials: out = ELU(P0 + P1 + bias)
__global__ void combine_k(const float* __restrict__ P0,
                          const float* __restrict__ P1,
                          const float* __restrict__ bias,
                          float* __restrict__ out, int total4) {
    int i = blockIdx.x * 256 + threadIdx.x;
    if (i >= total4) return;
    int e = i << 2;
    float4 a = *(const float4*)(P0 + e);
    float4 b = *(const float4*)(P1 + e);
    float4 bv = *(const float4*)(bias + (e & 511));
    float4 o;
    o.x = a.x + b.x + bv.x;
    o.y = a.y + b.y + bv.y;
    o.z = a.z + b.z + bv.z;
    o.w = a.w + b.w + bv.w;
    o.x = o.x > 0.f ? o.x : __expf(o.x) - 1.f;
    o.y = o.y > 0.f ? o.y : __expf(o.y) - 1.f;
    o.z = o.z > 0.f ? o.z : __expf(o.z) - 1.f;
    o.w = o.w > 0.f ? o.w : __expf(o.w) - 1.f;
    *(float4*)(out + e) = o;
}

// ------------------------------ attention ---------------------------------
__global__ __launch_bounds__(256) void alpha0_k(const float* __restrict__ h0,
                                                const float* __restrict__ att_s,
                                                const float* __restrict__ att_d,
                                                float* __restrict__ as_,
                                                float* __restrict__ ad_) {
    int n = blockIdx.x * 4 + (threadIdx.x >> 6);
    int l = threadIdx.x & 63;
    int h = l >> 3, i = l & 7;
    float ps = 0.f, pd = 0.f;
    #pragma unroll
    for (int c = 0; c < 64; c += 8) {
        float v = h0[(size_t)n * 512 + h * 64 + c + i];
        ps += v * att_s[h * 64 + c + i];
        pd += v * att_d[h * 64 + c + i];
    }
    #pragma unroll
    for (int off = 1; off < 8; off <<= 1) {
        ps += __shfl_xor(ps, off);
        pd += __shfl_xor(pd, off);
    }
    if (i == 0) {
        as_[n * 8 + h] = ps;
        ad_[n * 8 + h] = pd;
    }
}

__global__ __launch_bounds__(256) void prep1_k(const float* __restrict__ W1,
                                               const float* __restrict__ as1,
                                               const float* __restrict__ ad1,
                                               float* __restrict__ ws1,
                                               float* __restrict__ wd1) {
    int k = blockIdx.x;
    int t = threadIdx.x;
    int h = t >> 5, lane = t & 31;
    float ps = 0.f, pd = 0.f;
    for (int c = lane; c < 512; c += 32) {
        float w = W1[(size_t)k * 4096 + h * 512 + c];
        ps += w * as1[h * 512 + c];
        pd += w * ad1[h * 512 + c];
    }
    #pragma unroll
    for (int off = 1; off < 32; off <<= 1) {
        ps += __shfl_xor(ps, off);
        pd += __shfl_xor(pd, off);
    }
    if (lane == 0) {
        ws1[k * 8 + h] = ps;
        wd1[k * 8 + h] = pd;
    }
}

// -------- layer-0 node kernel: softmax + aggregate + ELU + fused alpha1 ----
__global__ __launch_bounds__(256) void node0_k(
    const float* __restrict__ h0, const float* __restrict__ asrc,
    const float* __restrict__ adst, const int* __restrict__ indptr,
    const int* __restrict__ csr, const float* __restrict__ b0,
    const float* __restrict__ ws1, const float* __restrict__ wd1,
    float* __restrict__ hl0, float* __restrict__ as1, float* __restrict__ ad1) {
    int d = (blockIdx.x & 7) * (NNODES / 8) + (blockIdx.x >> 3);
    int t = threadIdx.x;
    __shared__ float red[256];
    __shared__ float m_s[8], rz_s[8];
    __shared__ float al[32 * 8];
    __shared__ int sl[32];
    __shared__ float comb[128 * 4];
    __shared__ float pw[2][16];
    int e0 = indptr[d], ne = indptr[d + 1] - e0;
    int h = t & 7, slice = t >> 3;
    float adh = adst[d * 8 + h];

    float mx = -3.0e38f;
    for (int e = slice; e < ne + 1; e += 32) {
        int s = (e < ne) ? csr[e0 + e] : d;
        float v = asrc[s * 8 + h] + adh;
        v = v > 0.f ? v : 0.2f * v;
        mx = fmaxf(mx, v);
    }
    red[t] = mx;
    __syncthreads();
    #pragma unroll
    for (int off = 128; off >= 8; off >>= 1) {
        if (t < off) red[t] = fmaxf(red[t], red[t + off]);
        __syncthreads();
    }
    if (t < 8) m_s[t] = red[t];
    __syncthreads();

    float mh = m_s[h];
    float zs = 0.f;
    for (int e = slice; e < ne + 1; e += 32) {
        int s = (e < ne) ? csr[e0 + e] : d;
        float v = asrc[s * 8 + h] + adh;
        v = v > 0.f ? v : 0.2f * v;
        zs += __expf(v - mh);
    }
    red[t] = zs;
    __syncthreads();
    #pragma unroll
    for (int off = 128; off >= 8; off >>= 1) {
        if (t < off) red[t] += red[t + off];
        __syncthreads();
    }
    if (t < 8) rz_s[t] = 1.0f / (red[t] + 1e-16f);
    __syncthreads();

    int half = t >> 7, c4 = t & 127;
    int hc = c4 >> 4;
    float4 acc4 = make_float4(0.f, 0.f, 0.f, 0.f);
    for (int eb = 0; eb < ne + 1; eb += 32) {
        int nn = min(32, ne + 1 - eb);
        __syncthreads();
        if (t < nn * 8) {  // t = el*8 + hh
            int el = t >> 3, hh = t & 7;
            int s = (eb + el < ne) ? csr[e0 + eb + el] : d;
            if (hh == 0) sl[el] = s;
            float v = asrc[s * 8 + hh] + adst[d * 8 + hh];
            v = v > 0.f ? v : 0.2f * v;
            al[t] = __expf(v - m_s[hh]) * rz_s[hh];
        }
        __syncthreads();
        for (int el = half; el < nn; el += 2) {
            int s = sl[el];
            float a = al[el * 8 + hc];
            float4 v = *(const float4*)(h0 + ((size_t)s << 9) + 4 * c4);
            acc4.x = fmaf(a, v.x, acc4.x);
            acc4.y = fmaf(a, v.y, acc4.y);
            acc4.z = fmaf(a, v.z, acc4.z);
            acc4.w = fmaf(a, v.w, acc4.w);
        }
    }
    if (half) *(float4*)&comb[c4 * 4] = acc4;
    __syncthreads();
    if (!half) {
        float4 c2 = *(const float4*)&comb[c4 * 4];
        float4 bv = *(const float4*)(b0 + 4 * c4);
        float4 o;
        o.x = acc4.x + c2.x + bv.x;
        o.y = acc4.y + c2.y + bv.y;
        o.z = acc4.z + c2.z + bv.z;
        o.w = acc4.w + c2.w + bv.w;
        o.x = o.x > 0.f ? o.x : __expf(o.x) - 1.f;
        o.y = o.y > 0.f ? o.y : __expf(o.y) - 1.f;
        o.z = o.z > 0.f ? o.z : __expf(o.z) - 1.f;
        o.w = o.w > 0.f ? o.w : __expf(o.w) - 1.f;
        *(float4*)(hl0 + ((size_t)d << 9) + 4 * c4) = o;

        float ps[8] = {}, pd[8] = {};
        float oq[4] = {o.x, o.y, o.z, o.w};
        #pragma unroll
        for (int q = 0; q < 4; q++) {
            const float4* w4 = (const float4*)(ws1 + (size_t)(4 * c4 + q) * 8);
            const float4* v4 = (const float4*)(wd1 + (size_t)(4 * c4 + q) * 8);
            float4 wa = w4[0], wb = w4[1];
            float4 va = v4[0], vb = v4[1];
            ps[0] = fmaf(oq[q], wa.x, ps[0]);
            ps[1] = fmaf(oq[q], wa.y, ps[1]);
            ps[2] = fmaf(oq[q], wa.z, ps[2]);
            ps[3] = fmaf(oq[q], wa.w, ps[3]);
            ps[4] = fmaf(oq[q], wb.x, ps[4]);
            ps[5] = fmaf(oq[q], wb.y, ps[5]);
            ps[6] = fmaf(oq[q], wb.z, ps[6]);
            ps[7] = fmaf(oq[q], wb.w, ps[7]);
            pd[0] = fmaf(oq[q], va.x, pd[0]);
            pd[1] = fmaf(oq[q], va.y, pd[1]);
            pd[2] = fmaf(oq[q], va.z, pd[2]);
            pd[3] = fmaf(oq[q], va.w, pd[3]);
            pd[4] = fmaf(oq[q], vb.x, pd[4]);
            pd[5] = fmaf(oq[q], vb.y, pd[5]);
            pd[6] = fmaf(oq[q], vb.z, pd[6]);
            pd[7] = fmaf(oq[q], vb.w, pd[7]);
        }
        #pragma unroll
        for (int off = 1; off < 64; off <<= 1) {
            #pragma unroll
            for (int hh = 0; hh < 8; hh++) {
                ps[hh] += __shfl_xor(ps[hh], off);
                pd[hh] += __shfl_xor(pd[hh], off);
            }
        }
        if ((t & 63) == 0) {
            int wv = t >> 6;
            #pragma unroll
            for (int hh = 0; hh < 8; hh++) {
                pw[wv][hh] = ps[hh];
                pw[wv][8 + hh] = pd[hh];
            }
        }
    }
    __syncthreads();
    if (t < 8) as1[(size_t)d * 8 + t] = pw[0][t] + pw[1][t];
    else if (t < 16) ad1[(size_t)d * 8 + t - 8] = pw[0][t] + pw[1][t];
}

// -------- layer-1 node kernel: softmax + per-head aggregate -> split bf16 ---
__global__ __launch_bounds__(256) void node1_k(const float* __restrict__ hl0,
                                               const float* __restrict__ asrc,
                                               const float* __restrict__ adst,
                                               const int* __restrict__ indptr,
                                               const int* __restrict__ csr,
                                               u16* __restrict__ aggh,
                                               u16* __restrict__ aggl,
                                               int base, int ch) {
    int dl = (blockIdx.x & 7) * (ch >> 3) + (blockIdx.x >> 3);
    int d = base + dl;
    int t = threadIdx.x;
    __shared__ float red[256];
    __shared__ float m_s[8], rz_s[8];
    __shared__ float al[32 * 8];
    __shared__ int sl[32];
    __shared__ float comb1[8][128 * 4];
    int e0 = indptr[d], ne = indptr[d + 1] - e0;
    int h = t & 7, slice = t >> 3;
    float adh = adst[d * 8 + h];

    float mx = -3.0e38f;
    for (int e = slice; e < ne + 1; e += 32) {
        int s = (e < ne) ? csr[e0 + e] : d;
        float v = asrc[s * 8 + h] + adh;
        v = v > 0.f ? v : 0.2f * v;
        mx = fmaxf(mx, v);
    }
    red[t] = mx;
    __syncthreads();
    #pragma unroll
    for (int off = 128; off >= 8; off >>= 1) {
        if (t < off) red[t] = fmaxf(red[t], red[t + off]);
        __syncthreads();
    }
    if (t < 8) m_s[t] = red[t];
    __syncthreads();

    float mh = m_s[h];
    float zs = 0.f;
    for (int e = slice; e < ne + 1; e += 32) {
        int s = (e < ne) ? csr[e0 + e] : d;
        float v = asrc[s * 8 + h] + adh;
        v = v > 0.f ? v : 0.2f * v;
        zs += __expf(v - mh);
    }
    red[t] = zs;
    __syncthreads();
    #pragma unroll
    for (int off = 128; off >= 8; off >>= 1) {
        if (t < off) red[t] += red[t + off];
        __syncthreads();
    }
    if (t < 8) rz_s[t] = 1.0f / (red[t] + 1e-16f);
    __syncthreads();

    int half = t >> 7, c4 = t & 127;
    float4 acc[8];
    #pragma unroll
    for (int hh = 0; hh < 8; hh++) acc[hh] = make_float4(0.f, 0.f, 0.f, 0.f);

    for (int eb = 0; eb < ne + 1; eb += 32) {
        int nn = min(32, ne + 1 - eb);
        __syncthreads();
        if (t < nn * 8) {
            int el = t >> 3, hh = t & 7;
            int s = (eb + el < ne) ? csr[e0 + eb + el] : d;
            if (hh == 0) sl[el] = s;
            float v = asrc[s * 8 + hh] + adst[d * 8 + hh];
            v = v > 0.f ? v : 0.2f * v;
            al[t] = __expf(v - m_s[hh]) * rz_s[hh];
        }
        __syncthreads();
        for (int el = half; el < nn; el += 2) {
            int s = sl[el];
            float4 v = *(const float4*)(hl0 + ((size_t)s << 9) + 4 * c4);
            float4 a0 = *(const float4*)&al[el * 8];
            float4 a1 = *(const float4*)&al[el * 8 + 4];
            float av[8] = {a0.x, a0.y, a0.z, a0.w, a1.x, a1.y, a1.z, a1.w};
            #pragma unroll
            for (int hh = 0; hh < 8; hh++) {
                acc[hh].x = fmaf(av[hh], v.x, acc[hh].x);
                acc[hh].y = fmaf(av[hh], v.y, acc[hh].y);
                acc[hh].z = fmaf(av[hh], v.z, acc[hh].z);
                acc[hh].w = fmaf(av[hh], v.w, acc[hh].w);
            }
        }
    }
    if (half) {
        #pragma unroll
        for (int hh = 0; hh < 8; hh++) *(float4*)&comb1[hh][c4 * 4] = acc[hh];
    }
    __syncthreads();
    if (!half) {
        #pragma unroll
        for (int hh = 0; hh < 8; hh++) {
            float4 c2 = *(const float4*)&comb1[hh][c4 * 4];
            float4 v;
            v.x = acc[hh].x + c2.x;
            v.y = acc[hh].y + c2.y;
            v.z = acc[hh].z + c2.z;
            v.w = acc[hh].w + c2.w;
            u16 hx[4], lx[4];
            split2(v.x, hx[0], lx[0]);
            split2(v.y, hx[1], lx[1]);
            split2(v.z, hx[2], lx[2]);
            split2(v.w, hx[3], lx[3]);
            size_t ob = (size_t)dl * 4096 + hh * 512 + 4 * c4;
            *(ushort4*)(aggh + ob) = make_ushort4(hx[0], hx[1], hx[2], hx[3]);
            *(ushort4*)(aggl + ob) = make_ushort4(lx[0], lx[1], lx[2], lx[3]);
        }
    }
}

// ------------------------------- launcher ----------------------------------
extern "C" void kernel_launch(void* const* d_in, const int* in_sizes, int n_in,
                              void* d_out, int out_size, void* d_ws, size_t ws_size,
                              hipStream_t stream) {
    const float* x = (const float*)d_in[0];
    const int* ei = (const int*)d_in[1];
    const float* W0 = (const float*)d_in[2];
    const float* at_s0 = (const float*)d_in[3];
    const float* at_d0 = (const float*)d_in[4];
    const float* b0 = (const float*)d_in[5];
    const float* W1 = (const float*)d_in[6];
    const float* at_s1 = (const float*)d_in[7];
    const float* at_d1 = (const float*)d_in[8];
    const float* b1 = (const float*)d_in[9];
    float* out = (float*)d_out;

    const int N = NNODES;
    const int E = in_sizes[1] / 2;
    const int* esrc = ei;
    const int* edst = ei + E;

    char* p = (char*)d_ws;
    auto carve = [&](size_t bytes) -> void* {
        void* r = (void*)p;
        p += ((bytes + 255) & ~(size_t)255);
        return r;
    };
    float* h0 = (float*)carve((size_t)N * 512 * 4);
    float* hl0 = (float*)carve((size_t)N * 512 * 4);
    float* as0 = (float*)carve((size_t)N * 8 * 4);
    float* ad0 = (float*)carve((size_t)N * 8 * 4);
    float* as1 = (float*)carve((size_t)N * 8 * 4);
    float* ad1 = (float*)carve((size_t)N * 8 * 4);
    int* deg = (int*)carve((size_t)N * 4);
    int* indptr = (int*)carve((size_t)(N + 1) * 4);
    int* cursor = (int*)carve((size_t)N * 4);
    int* csr = (int*)carve((size_t)E * 4);
    float* ws1 = (float*)carve(512 * 8 * 4);
    float* wd1 = (float*)carve(512 * 8 * 4);
    u16* xh = (u16*)carve((size_t)N * 512 * 2);
    u16* xl = (u16*)carve((size_t)N * 512 * 2);
    u16* W0h = (u16*)carve((size_t)512 * 512 * 2);
    u16* W0l = (u16*)carve((size_t)512 * 512 * 2);
    u16* B1h = (u16*)carve((size_t)512 * 4096 * 2);
    u16* B1l = (u16*)carve((size_t)512 * 4096 * 2);
    size_t used = (size_t)(p - (char*)d_ws);

    // chunk size: agg (CH*16384 B) + K-split partials (CH*4096 B)
    int CH = 1024;
    const int cands[5] = {16384, 8192, 4096, 2048, 1024};
    for (int ci = 0; ci < 5; ci++) {
        if (ws_size >= used + (size_t)cands[ci] * (16384 + 4096) + 2048) {
            CH = cands[ci];
            break;
        }
    }
    u16* aggh = (u16*)carve((size_t)CH * 4096 * 2);
    u16* aggl = (u16*)carve((size_t)CH * 4096 * 2);
    float* P0 = (float*)carve((size_t)CH * 512 * 4);
    float* P1 = (float*)carve((size_t)CH * 512 * 4);

    // CSR build
    zero_k<<<(N + 255) / 256, 256, 0, stream>>>(deg, N);
    count_k<<<(E + 255) / 256, 256, 0, stream>>>(edst, E, deg);
    scan_k<<<1, 1024, 0, stream>>>(deg, indptr, cursor, N);
    scatter_k<<<(E + 255) / 256, 256, 0, stream>>>(esrc, edst, E, cursor, csr);

    // operand prep (split bf16) + folded layer-1 attention weights
    prepx_k<<<(N * 512 / 4 + 255) / 256, 256, 0, stream>>>(x, xh, xl);
    prepW0_k<<<512, 256, 0, stream>>>(W0, W0h, W0l);
    prepW1_k<<<512, 256, 0, stream>>>(W1, B1h, B1l);
    prep1_k<<<512, 256, 0, stream>>>(W1, at_s1, at_d1, ws1, wd1);

    // Layer 0
    mgemm2_k<0, 1><<<dim3(4, N / 128), 256, 0, stream>>>(
        xh, xl, W0h, W0l, h0, 512, nullptr, nullptr, nullptr);
    alpha0_k<<<N / 4, 256, 0, stream>>>(h0, at_s0, at_d0, as0, ad0);
    node0_k<<<N, 256, 0, stream>>>(h0, as0, ad0, indptr, csr, b0, ws1, wd1,
                                   hl0, as1, ad1);

    // Layer 1: aggregate per chunk, K-split GEMM, combine(+b1, ELU) into d_out
    for (int base = 0; base < N; base += CH) {
        node1_k<<<CH, 256, 0, stream>>>(hl0, as1, ad1, indptr, csr, aggh, aggl,
                                        base, CH);
        mgemm2_k<1, 2><<<dim3(4, CH / 128, 2), 256, 0, stream>>>(
            aggh, aggl, B1h, B1l, nullptr, 4096, nullptr, P0, P1);
        combine_k<<<CH / 2, 256, 0, stream>>>(P0, P1, b1,
                                              out + (size_t)base * 512, CH * 128);
    }
}

// Round 7
// 1037.378 us; speedup vs baseline: 1.0864x; 1.0864x over previous
//
#include <hip/hip_runtime.h>
#include <hip/hip_bf16.h>

// ---------------------------------------------------------------------------
// GAT 2-layer, N=16384 nodes, D=512, H=8, E=524288 edges (+self loops)
// GEMMs: split-bf16 3-term MFMA (32x32x16), slot-major LDS, global_load_lds,
// double-buffered (1 barrier/K-tile), K-split so grid >= 2 blocks/CU,
// partials alias dead h0. Node kernels: CSR softmax + float4 gather,
// XCD-pinned per graph. alpha1 fused into node0.
// ---------------------------------------------------------------------------

#define NNODES 16384

typedef unsigned short u16;
typedef unsigned int u32;
typedef __attribute__((ext_vector_type(8))) __bf16 bf16x8;
typedef __attribute__((ext_vector_type(4))) float f32x4;
typedef __attribute__((ext_vector_type(16))) float f32x16;

__device__ __forceinline__ u16 f2bf(float v) {
    u32 u = __builtin_bit_cast(u32, v);
    u32 r = (u + 0x7fffu + ((u >> 16) & 1u)) >> 16;
    return (u16)r;
}
__device__ __forceinline__ float bf2f(u16 s) {
    u32 u = ((u32)s) << 16;
    return __builtin_bit_cast(float, u);
}
__device__ __forceinline__ void split2(float v, u16& h, u16& l) {
    h = f2bf(v);
    l = f2bf(v - bf2f(h));
}

// async global->LDS, 16B per lane; LDS dest is wave-uniform base + lane*16
__device__ __forceinline__ void gload_lds16(const u16* g, u16* l) {
    __builtin_amdgcn_global_load_lds(
        (__attribute__((address_space(1))) void*)(void*)(g),
        (__attribute__((address_space(3))) void*)(void*)(l), 16, 0, 0);
}

// ------------------------------ CSR build ---------------------------------
__global__ void zero_k(int* p, int n) {
    int i = blockIdx.x * 256 + threadIdx.x;
    if (i < n) p[i] = 0;
}

__global__ void count_k(const int* __restrict__ dst, int E, int* __restrict__ deg) {
    int i = blockIdx.x * 256 + threadIdx.x;
    if (i < E) atomicAdd(&deg[dst[i]], 1);
}

__global__ __launch_bounds__(1024) void scan_k(const int* __restrict__ deg,
                                               int* __restrict__ indptr,
                                               int* __restrict__ cursor, int n) {
    __shared__ int sums[1024];
    int t = threadIdx.x;
    int base = t * 16;
    int local[16];
    int s = 0;
    #pragma unroll
    for (int i = 0; i < 16; i++) { local[i] = s; s += deg[base + i]; }
    sums[t] = s;
    __syncthreads();
    for (int off = 1; off < 1024; off <<= 1) {
        int v = (t >= off) ? sums[t - off] : 0;
        __syncthreads();
        sums[t] += v;
        __syncthreads();
    }
    int base_sum = (t == 0) ? 0 : sums[t - 1];
    #pragma unroll
    for (int i = 0; i < 16; i++) {
        int v = base_sum + local[i];
        indptr[base + i] = v;
        cursor[base + i] = v;
    }
    if (t == 1023) indptr[n] = base_sum + s;
}

__global__ void scatter_k(const int* __restrict__ src, const int* __restrict__ dst,
                          int E, int* __restrict__ cursor, int* __restrict__ csr) {
    int i = blockIdx.x * 256 + threadIdx.x;
    if (i < E) {
        int pos = atomicAdd(&cursor[dst[i]], 1);
        csr[pos] = src[i];
    }
}

// ------------------------- split-bf16 prep kernels -------------------------
__global__ void prepx_k(const float* __restrict__ x, u16* __restrict__ xh,
                        u16* __restrict__ xl) {
    int idx = blockIdx.x * 256 + threadIdx.x;
    int e = idx << 2;
    int n = e >> 9, k = e & 511;
    int g = n >> 10, s = n & 1023;
    float4 v = *(const float4*)(x + ((size_t)(s * 16 + g) << 9) + k);
    u16 h[4], l[4];
    split2(v.x, h[0], l[0]);
    split2(v.y, h[1], l[1]);
    split2(v.z, h[2], l[2]);
    split2(v.w, h[3], l[3]);
    size_t o = ((size_t)n << 9) + k;
    *(ushort4*)(xh + o) = make_ushort4(h[0], h[1], h[2], h[3]);
    *(ushort4*)(xl + o) = make_ushort4(l[0], l[1], l[2], l[3]);
}

// W0t[n][k] = W0[k][n], tiled 64x64 transpose through LDS (coalesced both ways)
__global__ __launch_bounds__(256) void prepW0t_k(const float* __restrict__ W0,
                                                 u16* __restrict__ Wh,
                                                 u16* __restrict__ Wl) {
    __shared__ u32 tile[64][65];
    int b = blockIdx.x;
    int kt = (b >> 3) * 64, nt = (b & 7) * 64;
    int t = threadIdx.x;
    #pragma unroll
    for (int i = 0; i < 16; i++) {
        int idx = i * 256 + t;
        int r = idx >> 6, c = idx & 63;
        float v = W0[(size_t)(kt + r) * 512 + nt + c];
        u16 h, l;
        split2(v, h, l);
        tile[r][c] = ((u32)h << 16) | l;
    }
    __syncthreads();
    #pragma unroll
    for (int i = 0; i < 8; i++) {
        int idx = i * 256 + t;
        int r = idx >> 5, c2 = (idx & 31) * 2;
        u32 p0 = tile[c2][r], p1 = tile[c2 + 1][r];
        size_t o = (size_t)(nt + r) * 512 + kt + c2;
        *(ushort2*)(Wh + o) = make_ushort2((u16)(p0 >> 16), (u16)(p1 >> 16));
        *(ushort2*)(Wl + o) = make_ushort2((u16)(p0 & 0xffff), (u16)(p1 & 0xffff));
    }
}

// B1t[c][h*512+k] = W1[k][h*512+c]/8, per-head tiled 64x64 transpose
__global__ __launch_bounds__(256) void prepW1t_k(const float* __restrict__ W1,
                                                 u16* __restrict__ Bh,
                                                 u16* __restrict__ Bl) {
    __shared__ u32 tile[64][65];
    int b = blockIdx.x;
    int hh = b >> 6;
    int rem = b & 63;
    int kt = (rem >> 3) * 64, ct = (rem & 7) * 64;
    int t = threadIdx.x;
    #pragma unroll
    for (int i = 0; i < 16; i++) {
        int idx = i * 256 + t;
        int r = idx >> 6, c = idx & 63;
        float v = W1[(size_t)(kt + r) * 4096 + hh * 512 + ct + c] * 0.125f;
        u16 h, l;
        split2(v, h, l);
        tile[r][c] = ((u32)h << 16) | l;
    }
    __syncthreads();
    #pragma unroll
    for (int i = 0; i < 8; i++) {
        int idx = i * 256 + t;
        int r = idx >> 5, c2 = (idx & 31) * 2;
        u32 p0 = tile[c2][r], p1 = tile[c2 + 1][r];
        size_t o = (size_t)(ct + r) * 4096 + hh * 512 + kt + c2;
        *(ushort2*)(Bh + o) = make_ushort2((u16)(p0 >> 16), (u16)(p1 >> 16));
        *(ushort2*)(Bl + o) = make_ushort2((u16)(p0 & 0xffff), (u16)(p1 & 0xffff));
    }
}

// ---------------------------------------------------------------------------
// Split-bf16 MFMA GEMM: C[M,512] = A[M,K] @ Bt[512,K]^T  (3 MFMA per frag pair)
// BM=128, BN=128, BK=32, 4 waves (2x2, 64x64 each), mfma_f32_32x32x16.
// Slot-major LDS (chunk idx = slot*128 + row -> consecutive-chunk reads,
// conflict-free). Double-buffered: stage(next) issued BEFORE compute(cur),
// single barrier per K-tile (vmcnt(0) drain at the barrier covers the loads
// that had the whole MFMA phase to land).
// SPLIT=0: direct store to C. SPLIT=1: K split over blockIdx.z into P.
// ---------------------------------------------------------------------------
template <int SPLIT>
__global__ __launch_bounds__(256) void mgemm3_k(
    const u16* __restrict__ Ah, const u16* __restrict__ Al,
    const u16* __restrict__ Bh, const u16* __restrict__ Bl,
    float* __restrict__ C, int K, float* __restrict__ P) {
    __shared__ u16 sm0[16384];  // 32 KB: A_h|A_l|B_h|B_l planes of 4096 u16
    __shared__ u16 sm1[16384];

    int t = threadIdx.x;
    int lane = t & 63, w = t >> 6;
    int wr = w >> 1, wc = w & 1;
    int row0 = blockIdx.y * 128, col0 = blockIdx.x * 128;
    int kcnt = SPLIT ? (K / (int)gridDim.z) : K;
    int kbeg = SPLIT ? ((int)blockIdx.z * kcnt) : 0;

    f32x16 acc[2][2];
    #pragma unroll
    for (int i = 0; i < 2; i++)
        #pragma unroll
        for (int j = 0; j < 2; j++)
            #pragma unroll
            for (int q = 0; q < 16; q++) acc[i][j][q] = 0.f;

    // staging role: one plane per wave, 8 segments of 1 KB each
    const u16* gb;
    int po, g0;
    if (w == 0) { gb = Ah; po = 0; g0 = row0; }
    else if (w == 1) { gb = Al; po = 4096; g0 = row0; }
    else if (w == 2) { gb = Bh; po = 8192; g0 = col0; }
    else { gb = Bl; po = 12288; g0 = col0; }

    auto stage = [&](u16* sm, int k0) {
        // seg s: rows (s&1)*64+lane, k-slot s>>1 -> chunks (s>>1)*128 + row
        #pragma unroll
        for (int s = 0; s < 8; s++) {
            const u16* g = gb + (size_t)(g0 + (s & 1) * 64 + lane) * K + k0 +
                           ((s >> 1) << 3);
            gload_lds16(g, sm + po + s * 512);
        }
    };

    int r32 = lane & 31, kb5 = lane >> 5;
    auto compute = [&](const u16* sm) {
        #pragma unroll
        for (int ks = 0; ks < 2; ks++) {
            int slot = ks * 2 + kb5;
            bf16x8 a_h[2], a_l[2], b_h[2], b_l[2];
            #pragma unroll
            for (int i = 0; i < 2; i++) {
                int off = (slot * 128 + wr * 64 + i * 32 + r32) * 8;
                a_h[i] = *(const bf16x8*)(sm + off);
                a_l[i] = *(const bf16x8*)(sm + 4096 + off);
            }
            #pragma unroll
            for (int j = 0; j < 2; j++) {
                int off = (slot * 128 + wc * 64 + j * 32 + r32) * 8;
                b_h[j] = *(const bf16x8*)(sm + 8192 + off);
                b_l[j] = *(const bf16x8*)(sm + 12288 + off);
            }
            #pragma unroll
            for (int i = 0; i < 2; i++)
                #pragma unroll
                for (int j = 0; j < 2; j++) {
                    acc[i][j] = __builtin_amdgcn_mfma_f32_32x32x16_bf16(
                        a_l[i], b_h[j], acc[i][j], 0, 0, 0);
                    acc[i][j] = __builtin_amdgcn_mfma_f32_32x32x16_bf16(
                        a_h[i], b_l[j], acc[i][j], 0, 0, 0);
                    acc[i][j] = __builtin_amdgcn_mfma_f32_32x32x16_bf16(
                        a_h[i], b_h[j], acc[i][j], 0, 0, 0);
                }
        }
    };

    int nkt = kcnt >> 5;
    stage(sm0, kbeg);
    __syncthreads();
    for (int kt = 0; kt < nkt; kt += 2) {
        if (kt + 1 < nkt) stage(sm1, kbeg + (kt + 1) * 32);
        compute(sm0);
        __syncthreads();
        if (kt + 2 < nkt) stage(sm0, kbeg + (kt + 2) * 32);
        if (kt + 1 < nkt) compute(sm1);
        __syncthreads();
    }

    // C/D layout 32x32: col = lane&31, row = (q&3) + 8*(q>>2) + 4*(lane>>5)
    #pragma unroll
    for (int i = 0; i < 2; i++) {
        #pragma unroll
        for (int j = 0; j < 2; j++) {
            int col = col0 + wc * 64 + j * 32 + r32;
            f32x16 v = acc[i][j];
            #pragma unroll
            for (int q = 0; q < 16; q++) {
                int row = row0 + wr * 64 + i * 32 + (q & 3) + ((q >> 2) << 3) +
                          (kb5 << 2);
                if (SPLIT) {
                    size_t M = (size_t)gridDim.y * 128;
                    P[((size_t)blockIdx.z * M + row) * 512 + col] = v[q];
                } else {
                    C[(size_t)row * 512 + col] = v[q];
                }
            }
        }
    }
}

// combine K-split partials: out = ELU(sum_bz P[bz] + bias)
__global__ void combine_k(const float* __restrict__ P,
                          const float* __restrict__ bias,
                          float* __restrict__ out, int CH, int NS) {
    int i = blockIdx.x * 256 + threadIdx.x;
    int total4 = CH * 128;
    if (i >= total4) return;
    int e = i << 2;
    size_t stride = (size_t)CH * 512;
    float4 s = *(const float4*)(P + e);
    for (int bz = 1; bz < NS; bz++) {
        float4 a = *(const float4*)(P + bz * stride + e);
        s.x += a.x; s.y += a.y; s.z += a.z; s.w += a.w;
    }
    float4 bv = *(const float4*)(bias + (e & 511));
    s.x += bv.x; s.y += bv.y; s.z += bv.z; s.w += bv.w;
    s.x = s.x > 0.f ? s.x : __expf(s.x) - 1.f;
    s.y = s.y > 0.f ? s.y : __expf(s.y) - 1.f;
    s.z = s.z > 0.f ? s.z : __expf(s.z) - 1.f;
    s.w = s.w > 0.f ? s.w : __expf(s.w) - 1.f;
    *(float4*)(out + e) = s;
}

// ------------------------------ attention ---------------------------------
__global__ __launch_bounds__(256) void alpha0_k(const float* __restrict__ h0,
                                                const float* __restrict__ att_s,
                                                const float* __restrict__ att_d,
                                                float* __restrict__ as_,
                                                float* __restrict__ ad_) {
    int n = blockIdx.x * 4 + (threadIdx.x >> 6);
    int l = threadIdx.x & 63;
    int h = l >> 3, i = l & 7;
    float ps = 0.f, pd = 0.f;
    #pragma unroll
    for (int c = 0; c < 64; c += 8) {
        float v = h0[(size_t)n * 512 + h * 64 + c + i];
        ps += v * att_s[h * 64 + c + i];
        pd += v * att_d[h * 64 + c + i];
    }
    #pragma unroll
    for (int off = 1; off < 8; off <<= 1) {
        ps += __shfl_xor(ps, off);
        pd += __shfl_xor(pd, off);
    }
    if (i == 0) {
        as_[n * 8 + h] = ps;
        ad_[n * 8 + h] = pd;
    }
}

__global__ __launch_bounds__(256) void prep1_k(const float* __restrict__ W1,
                                               const float* __restrict__ as1,
                                               const float* __restrict__ ad1,
                                               float* __restrict__ ws1,
                                               float* __restrict__ wd1) {
    int k = blockIdx.x;
    int t = threadIdx.x;
    int h = t >> 5, lane = t & 31;
    float ps = 0.f, pd = 0.f;
    for (int c = lane; c < 512; c += 32) {
        float w = W1[(size_t)k * 4096 + h * 512 + c];
        ps += w * as1[h * 512 + c];
        pd += w * ad1[h * 512 + c];
    }
    #pragma unroll
    for (int off = 1; off < 32; off <<= 1) {
        ps += __shfl_xor(ps, off);
        pd += __shfl_xor(pd, off);
    }
    if (lane == 0) {
        ws1[k * 8 + h] = ps;
        wd1[k * 8 + h] = pd;
    }
}

// -------- layer-0 node kernel: softmax + aggregate + ELU + fused alpha1 ----
__global__ __launch_bounds__(256) void node0_k(
    const float* __restrict__ h0, const float* __restrict__ asrc,
    const float* __restrict__ adst, const int* __restrict__ indptr,
    const int* __restrict__ csr, const float* __restrict__ b0,
    const float* __restrict__ ws1, const float* __restrict__ wd1,
    float* __restrict__ hl0, float* __restrict__ as1, float* __restrict__ ad1) {
    int d = (blockIdx.x & 7) * (NNODES / 8) + (blockIdx.x >> 3);
    int t = threadIdx.x;
    __shared__ float red[256];
    __shared__ float m_s[8], rz_s[8];
    __shared__ float al[32 * 8];
    __shared__ int sl[32];
    __shared__ float comb[128 * 4];
    __shared__ float pw[2][16];
    int e0 = indptr[d], ne = indptr[d + 1] - e0;
    int h = t & 7, slice = t >> 3;
    float adh = adst[d * 8 + h];

    float mx = -3.0e38f;
    for (int e = slice; e < ne + 1; e += 32) {
        int s = (e < ne) ? csr[e0 + e] : d;
        float v = asrc[s * 8 + h] + adh;
        v = v > 0.f ? v : 0.2f * v;
        mx = fmaxf(mx, v);
    }
    red[t] = mx;
    __syncthreads();
    #pragma unroll
    for (int off = 128; off >= 8; off >>= 1) {
        if (t < off) red[t] = fmaxf(red[t], red[t + off]);
        __syncthreads();
    }
    if (t < 8) m_s[t] = red[t];
    __syncthreads();

    float mh = m_s[h];
    float zs = 0.f;
    for (int e = slice; e < ne + 1; e += 32) {
        int s = (e < ne) ? csr[e0 + e] : d;
        float v = asrc[s * 8 + h] + adh;
        v = v > 0.f ? v : 0.2f * v;
        zs += __expf(v - mh);
    }
    red[t] = zs;
    __syncthreads();
    #pragma unroll
    for (int off = 128; off >= 8; off >>= 1) {
        if (t < off) red[t] += red[t + off];
        __syncthreads();
    }
    if (t < 8) rz_s[t] = 1.0f / (red[t] + 1e-16f);
    __syncthreads();

    int half = t >> 7, c4 = t & 127;
    int hc = c4 >> 4;
    float4 acc4 = make_float4(0.f, 0.f, 0.f, 0.f);
    for (int eb = 0; eb < ne + 1; eb += 32) {
        int nn = min(32, ne + 1 - eb);
        __syncthreads();
        if (t < nn * 8) {  // t = el*8 + hh
            int el = t >> 3, hh = t & 7;
            int s = (eb + el < ne) ? csr[e0 + eb + el] : d;
            if (hh == 0) sl[el] = s;
            float v = asrc[s * 8 + hh] + adst[d * 8 + hh];
            v = v > 0.f ? v : 0.2f * v;
            al[t] = __expf(v - m_s[hh]) * rz_s[hh];
        }
        __syncthreads();
        for (int el = half; el < nn; el += 2) {
            int s = sl[el];
            float a = al[el * 8 + hc];
            float4 v = *(const float4*)(h0 + ((size_t)s << 9) + 4 * c4);
            acc4.x = fmaf(a, v.x, acc4.x);
            acc4.y = fmaf(a, v.y, acc4.y);
            acc4.z = fmaf(a, v.z, acc4.z);
            acc4.w = fmaf(a, v.w, acc4.w);
        }
    }
    if (half) *(float4*)&comb[c4 * 4] = acc4;
    __syncthreads();
    if (!half) {
        float4 c2 = *(const float4*)&comb[c4 * 4];
        float4 bv = *(const float4*)(b0 + 4 * c4);
        float4 o;
        o.x = acc4.x + c2.x + bv.x;
        o.y = acc4.y + c2.y + bv.y;
        o.z = acc4.z + c2.z + bv.z;
        o.w = acc4.w + c2.w + bv.w;
        o.x = o.x > 0.f ? o.x : __expf(o.x) - 1.f;
        o.y = o.y > 0.f ? o.y : __expf(o.y) - 1.f;
        o.z = o.z > 0.f ? o.z : __expf(o.z) - 1.f;
        o.w = o.w > 0.f ? o.w : __expf(o.w) - 1.f;
        *(float4*)(hl0 + ((size_t)d << 9) + 4 * c4) = o;

        float ps[8] = {}, pd[8] = {};
        float oq[4] = {o.x, o.y, o.z, o.w};
        #pragma unroll
        for (int q = 0; q < 4; q++) {
            const float4* w4 = (const float4*)(ws1 + (size_t)(4 * c4 + q) * 8);
            const float4* v4 = (const float4*)(wd1 + (size_t)(4 * c4 + q) * 8);
            float4 wa = w4[0], wb = w4[1];
            float4 va = v4[0], vb = v4[1];
            ps[0] = fmaf(oq[q], wa.x, ps[0]);
            ps[1] = fmaf(oq[q], wa.y, ps[1]);
            ps[2] = fmaf(oq[q], wa.z, ps[2]);
            ps[3] = fmaf(oq[q], wa.w, ps[3]);
            ps[4] = fmaf(oq[q], wb.x, ps[4]);
            ps[5] = fmaf(oq[q], wb.y, ps[5]);
            ps[6] = fmaf(oq[q], wb.z, ps[6]);
            ps[7] = fmaf(oq[q], wb.w, ps[7]);
            pd[0] = fmaf(oq[q], va.x, pd[0]);
            pd[1] = fmaf(oq[q], va.y, pd[1]);
            pd[2] = fmaf(oq[q], va.z, pd[2]);
            pd[3] = fmaf(oq[q], va.w, pd[3]);
            pd[4] = fmaf(oq[q], vb.x, pd[4]);
            pd[5] = fmaf(oq[q], vb.y, pd[5]);
            pd[6] = fmaf(oq[q], vb.z, pd[6]);
            pd[7] = fmaf(oq[q], vb.w, pd[7]);
        }
        #pragma unroll
        for (int off = 1; off < 64; off <<= 1) {
            #pragma unroll
            for (int hh = 0; hh < 8; hh++) {
                ps[hh] += __shfl_xor(ps[hh], off);
                pd[hh] += __shfl_xor(pd[hh], off);
            }
        }
        if ((t & 63) == 0) {
            int wv = t >> 6;
            #pragma unroll
            for (int hh = 0; hh < 8; hh++) {
                pw[wv][hh] = ps[hh];
                pw[wv][8 + hh] = pd[hh];
            }
        }
    }
    __syncthreads();
    if (t < 8) as1[(size_t)d * 8 + t] = pw[0][t] + pw[1][t];
    else if (t < 16) ad1[(size_t)d * 8 + t - 8] = pw[0][t] + pw[1][t];
}

// -------- layer-1 node kernel: softmax + per-head aggregate -> split bf16 ---
__global__ __launch_bounds__(256) void node1_k(const float* __restrict__ hl0,
                                               const float* __restrict__ asrc,
                                               const float* __restrict__ adst,
                                               const int* __restrict__ indptr,
                                               const int* __restrict__ csr,
                                               u16* __restrict__ aggh,
                                               u16* __restrict__ aggl,
                                               int base, int ch) {
    int dl = (blockIdx.x & 7) * (ch >> 3) + (blockIdx.x >> 3);
    int d = base + dl;
    int t = threadIdx.x;
    __shared__ float red[256];
    __shared__ float m_s[8], rz_s[8];
    __shared__ float al[32 * 8];
    __shared__ int sl[32];
    __shared__ float comb1[8][128 * 4];
    int e0 = indptr[d], ne = indptr[d + 1] - e0;
    int h = t & 7, slice = t >> 3;
    float adh = adst[d * 8 + h];

    float mx = -3.0e38f;
    for (int e = slice; e < ne + 1; e += 32) {
        int s = (e < ne) ? csr[e0 + e] : d;
        float v = asrc[s * 8 + h] + adh;
        v = v > 0.f ? v : 0.2f * v;
        mx = fmaxf(mx, v);
    }
    red[t] = mx;
    __syncthreads();
    #pragma unroll
    for (int off = 128; off >= 8; off >>= 1) {
        if (t < off) red[t] = fmaxf(red[t], red[t + off]);
        __syncthreads();
    }
    if (t < 8) m_s[t] = red[t];
    __syncthreads();

    float mh = m_s[h];
    float zs = 0.f;
    for (int e = slice; e < ne + 1; e += 32) {
        int s = (e < ne) ? csr[e0 + e] : d;
        float v = asrc[s * 8 + h] + adh;
        v = v > 0.f ? v : 0.2f * v;
        zs += __expf(v - mh);
    }
    red[t] = zs;
    __syncthreads();
    #pragma unroll
    for (int off = 128; off >= 8; off >>= 1) {
        if (t < off) red[t] += red[t + off];
        __syncthreads();
    }
    if (t < 8) rz_s[t] = 1.0f / (red[t] + 1e-16f);
    __syncthreads();

    int half = t >> 7, c4 = t & 127;
    float4 acc[8];
    #pragma unroll
    for (int hh = 0; hh < 8; hh++) acc[hh] = make_float4(0.f, 0.f, 0.f, 0.f);

    for (int eb = 0; eb < ne + 1; eb += 32) {
        int nn = min(32, ne + 1 - eb);
        __syncthreads();
        if (t < nn * 8) {
            int el = t >> 3, hh = t & 7;
            int s = (eb + el < ne) ? csr[e0 + eb + el] : d;
            if (hh == 0) sl[el] = s;
            float v = asrc[s * 8 + hh] + adst[d * 8 + hh];
            v = v > 0.f ? v : 0.2f * v;
            al[t] = __expf(v - m_s[hh]) * rz_s[hh];
        }
        __syncthreads();
        for (int el = half; el < nn; el += 2) {
            int s = sl[el];
            float4 v = *(const float4*)(hl0 + ((size_t)s << 9) + 4 * c4);
            float4 a0 = *(const float4*)&al[el * 8];
            float4 a1 = *(const float4*)&al[el * 8 + 4];
            float av[8] = {a0.x, a0.y, a0.z, a0.w, a1.x, a1.y, a1.z, a1.w};
            #pragma unroll
            for (int hh = 0; hh < 8; hh++) {
                acc[hh].x = fmaf(av[hh], v.x, acc[hh].x);
                acc[hh].y = fmaf(av[hh], v.y, acc[hh].y);
                acc[hh].z = fmaf(av[hh], v.z, acc[hh].z);
                acc[hh].w = fmaf(av[hh], v.w, acc[hh].w);
            }
        }
    }
    if (half) {
        #pragma unroll
        for (int hh = 0; hh < 8; hh++) *(float4*)&comb1[hh][c4 * 4] = acc[hh];
    }
    __syncthreads();
    if (!half) {
        #pragma unroll
        for (int hh = 0; hh < 8; hh++) {
            float4 c2 = *(const float4*)&comb1[hh][c4 * 4];
            float4 v;
            v.x = acc[hh].x + c2.x;
            v.y = acc[hh].y + c2.y;
            v.z = acc[hh].z + c2.z;
            v.w = acc[hh].w + c2.w;
            u16 hx[4], lx[4];
            split2(v.x, hx[0], lx[0]);
            split2(v.y, hx[1], lx[1]);
            split2(v.z, hx[2], lx[2]);
            split2(v.w, hx[3], lx[3]);
            size_t ob = (size_t)dl * 4096 + hh * 512 + 4 * c4;
            *(ushort4*)(aggh + ob) = make_ushort4(hx[0], hx[1], hx[2], hx[3]);
            *(ushort4*)(aggl + ob) = make_ushort4(lx[0], lx[1], lx[2], lx[3]);
        }
    }
}

// ------------------------------- launcher ----------------------------------
extern "C" void kernel_launch(void* const* d_in, const int* in_sizes, int n_in,
                              void* d_out, int out_size, void* d_ws, size_t ws_size,
                              hipStream_t stream) {
    const float* x = (const float*)d_in[0];
    const int* ei = (const int*)d_in[1];
    const float* W0 = (const float*)d_in[2];
    const float* at_s0 = (const float*)d_in[3];
    const float* at_d0 = (const float*)d_in[4];
    const float* b0 = (const float*)d_in[5];
    const float* W1 = (const float*)d_in[6];
    const float* at_s1 = (const float*)d_in[7];
    const float* at_d1 = (const float*)d_in[8];
    const float* b1 = (const float*)d_in[9];
    float* out = (float*)d_out;

    const int N = NNODES;
    const int E = in_sizes[1] / 2;
    const int* esrc = ei;
    const int* edst = ei + E;

    char* p = (char*)d_ws;
    auto carve = [&](size_t bytes) -> void* {
        void* r = (void*)p;
        p += ((bytes + 255) & ~(size_t)255);
        return r;
    };
    float* h0 = (float*)carve((size_t)N * 512 * 4);   // aliased by P in layer 1
    float* hl0 = (float*)carve((size_t)N * 512 * 4);
    float* as0 = (float*)carve((size_t)N * 8 * 4);
    float* ad0 = (float*)carve((size_t)N * 8 * 4);
    float* as1 = (float*)carve((size_t)N * 8 * 4);
    float* ad1 = (float*)carve((size_t)N * 8 * 4);
    int* deg = (int*)carve((size_t)N * 4);
    int* indptr = (int*)carve((size_t)(N + 1) * 4);
    int* cursor = (int*)carve((size_t)N * 4);
    int* csr = (int*)carve((size_t)E * 4);
    float* ws1 = (float*)carve(512 * 8 * 4);
    float* wd1 = (float*)carve(512 * 8 * 4);
    u16* xh = (u16*)carve((size_t)N * 512 * 2);
    u16* xl = (u16*)carve((size_t)N * 512 * 2);
    u16* W0h = (u16*)carve((size_t)512 * 512 * 2);
    u16* W0l = (u16*)carve((size_t)512 * 512 * 2);
    u16* B1h = (u16*)carve((size_t)512 * 4096 * 2);
    u16* B1l = (u16*)carve((size_t)512 * 4096 * 2);
    size_t used = (size_t)(p - (char*)d_ws);

    // chunk size: only agg (16 KB/node); partials alias h0 (dead in layer 1)
    int CH = 1024;
    const int cands[5] = {16384, 8192, 4096, 2048, 1024};
    for (int ci = 0; ci < 5; ci++) {
        if (ws_size >= used + (size_t)cands[ci] * 16384 + 512) {
            CH = cands[ci];
            break;
        }
    }
    u16* aggh = (u16*)carve((size_t)CH * 4096 * 2);
    u16* aggl = (u16*)carve((size_t)CH * 4096 * 2);
    float* P = h0;               // NS*CH*512 floats = N*512 floats = |h0|
    int NS = N / CH;             // K-split factor -> grid always 512 blocks

    // CSR build
    zero_k<<<(N + 255) / 256, 256, 0, stream>>>(deg, N);
    count_k<<<(E + 255) / 256, 256, 0, stream>>>(edst, E, deg);
    scan_k<<<1, 1024, 0, stream>>>(deg, indptr, cursor, N);
    scatter_k<<<(E + 255) / 256, 256, 0, stream>>>(esrc, edst, E, cursor, csr);

    // operand prep (split bf16, coalesced tiled transposes) + folded weights
    prepx_k<<<(N * 512 / 4 + 255) / 256, 256, 0, stream>>>(x, xh, xl);
    prepW0t_k<<<64, 256, 0, stream>>>(W0, W0h, W0l);
    prepW1t_k<<<512, 256, 0, stream>>>(W1, B1h, B1l);
    prep1_k<<<512, 256, 0, stream>>>(W1, at_s1, at_d1, ws1, wd1);

    // Layer 0
    mgemm3_k<0><<<dim3(4, N / 128), 256, 0, stream>>>(
        xh, xl, W0h, W0l, h0, 512, nullptr);
    alpha0_k<<<N / 4, 256, 0, stream>>>(h0, at_s0, at_d0, as0, ad0);
    node0_k<<<N, 256, 0, stream>>>(h0, as0, ad0, indptr, csr, b0, ws1, wd1,
                                   hl0, as1, ad1);

    // Layer 1: aggregate per chunk, K-split GEMM into P, combine(+b1, ELU)
    for (int base = 0; base < N; base += CH) {
        node1_k<<<CH, 256, 0, stream>>>(hl0, as1, ad1, indptr, csr, aggh, aggl,
                                        base, CH);
        mgemm3_k<1><<<dim3(4, CH / 128, NS), 256, 0, stream>>>(
            aggh, aggl, B1h, B1l, nullptr, 4096, P);
        combine_k<<<CH / 2, 256, 0, stream>>>(P, b1, out + (size_t)base * 512,
                                              CH, NS);
    }
}